// Round 22
// baseline (304.171 us; speedup 1.0000x reference)
//
#include <hip/hip_runtime.h>
#include <math.h>

namespace {

constexpr int NB = 4, NSPK = 2, NCHN = 6;
constexpr int LSIG = 64000;
constexpr int NFFT = 512, HOPSZ = 128, NFREQ = 257;
constexpr int NT = 505;               // frames
constexpr int TAPS = 20;
constexpr int NG = NB * NFREQ * NSPK; // 2056 systems
constexpr int NSIG = NB * NSPK * NCHN; // 48 istft signals
constexpr float PI_F = 3.14159265358979323846f;
constexpr double LAMBDA_REG = 2e-4;
constexpr float FCP_EPS_F = 1e-3f;
constexpr int G_ELEMS = NG * TAPS * NCHN; // 246720 floats (real part only)
constexpr int NCH4 = (NT + 3) / 4;    // 127 four-frame chunks (last has 1)
constexpr int YPAD_N = TAPS + 2 + NT; // 527: [0..18]=0, [19+u]=Y[u], tail zeros
constexpr int NR_TILES = 55;          // 2x2 tiles of lower triangle (10x10 tile grid)
constexpr int NP_THREADS = 60;        // 10 p-pairs x 6 channels
constexpr int PM_BLOCKS_PER_B = (NFREQ * NT + 255) / 256;  // 507 blocks per batch

constexpr size_t WS_ALIGN = 256;
constexpr size_t align_up(size_t x) { return (x + WS_ALIGN - 1) & ~(WS_ALIGN - 1); }

// ws byte offsets
constexpr size_t SPH_B  = 0;                                        // [8][257][505] float2
constexpr size_t SPH_SZ = (size_t)NB * NSPK * NFREQ * NT * 8;
constexpr size_t SPHT_B = align_up(SPH_B + SPH_SZ);                 // [8][505][257] float2
constexpr size_t MXS_B  = align_up(SPHT_B + SPH_SZ);                // [24][257][505] float2
constexpr size_t MXS_SZ = (size_t)NB * NCHN * NFREQ * NT * 8;
constexpr size_t POW_B  = align_up(MXS_B + MXS_SZ);                 // [4][257][505] float
constexpr size_t POW_SZ = (size_t)NB * NFREQ * NT * 4;
constexpr size_t MX_B   = align_up(POW_B + POW_SZ);                 // [4] float
constexpr size_t R_B    = align_up(MX_B + (size_t)NB * 4);          // [2056][400] float2
constexpr size_t R_SZ   = (size_t)NG * TAPS * TAPS * 8;
constexpr size_t P_B    = align_up(R_B + R_SZ);                     // [2056][120] float2
constexpr size_t P_SZ   = (size_t)NG * TAPS * NCHN * 8;
constexpr size_t GCT_B  = align_up(P_B + P_SZ);                     // [8][20][6][257] float2
constexpr size_t GCT_SZ = (size_t)NB * NSPK * TAPS * NCHN * NFREQ * 8;
constexpr size_t FRM_B  = align_up(GCT_B + GCT_SZ);                 // [48][505][512] float

__device__ __forceinline__ int rev9(int n) { return (int)(__brev((unsigned)n) >> 23); }

// Quad in-LDS radix-2 DIT FFT, stage-pair fused (radix-4 style). Barriers 9->5.
__device__ __forceinline__ void fft512_quad(float2* buf, int tid, float sign) {
#pragma unroll
  for (int s = 1; s <= 7; s += 2) {
    int h = 1 << (s - 1);
    int idx = tid & 127;
    int jb = (tid >> 7) * 2;          // this thread's buffer pair
    int pos = idx & (h - 1);
    int blk = idx >> (s - 1);
    int i0 = (blk << (s + 1)) + pos;
    float angA = sign * 2.0f * PI_F * (float)pos / (float)(2 * h);
    float angB = 0.5f * angA;
    float snA, csA, snB, csB;
    __sincosf(angA, &snA, &csA);
    __sincosf(angB, &snB, &csB);
    float csB2 = -sign * snB, snB2 = sign * csB;  // tw_B * (sign*i), exact
#pragma unroll
    for (int jj = 0; jj < 2; ++jj) {
      float2* bb = buf + (jb + jj) * NFFT;
      float2 e0 = bb[i0], e1 = bb[i0 + h], e2 = bb[i0 + 2 * h], e3 = bb[i0 + 3 * h];
      float2 t1 = make_float2(e1.x * csA - e1.y * snA, e1.x * snA + e1.y * csA);
      float2 t3 = make_float2(e3.x * csA - e3.y * snA, e3.x * snA + e3.y * csA);
      float2 p0 = make_float2(e0.x + t1.x, e0.y + t1.y);
      float2 p1 = make_float2(e0.x - t1.x, e0.y - t1.y);
      float2 p2 = make_float2(e2.x + t3.x, e2.y + t3.y);
      float2 p3 = make_float2(e2.x - t3.x, e2.y - t3.y);
      float2 u2 = make_float2(p2.x * csB - p2.y * snB, p2.x * snB + p2.y * csB);
      float2 u3 = make_float2(p3.x * csB2 - p3.y * snB2, p3.x * snB2 + p3.y * csB2);
      bb[i0]         = make_float2(p0.x + u2.x, p0.y + u2.y);
      bb[i0 + 2 * h] = make_float2(p0.x - u2.x, p0.y - u2.y);
      bb[i0 + h]     = make_float2(p1.x + u3.x, p1.y + u3.y);
      bb[i0 + 3 * h] = make_float2(p1.x - u3.x, p1.y - u3.y);
    }
    __syncthreads();
  }
  {
    float ang = sign * 2.0f * PI_F * (float)tid / 512.0f;
    float sn, cs;
    __sincosf(ang, &sn, &cs);
#pragma unroll
    for (int j = 0; j < 4; ++j) {
      float2* bb = buf + j * NFFT;
      float2 u = bb[tid], v = bb[tid + 256];
      float2 vw = make_float2(v.x * cs - v.y * sn, v.x * sn + v.y * cs);
      bb[tid] = make_float2(u.x + vw.x, u.y + vw.y);
      bb[tid + 256] = make_float2(u.x - vw.x, u.y - vw.y);
    }
    __syncthreads();
  }
}

// ---------------- STFT (quad-frame radix-2 FFT) ----------------
__global__ void stft_kernel(const float* __restrict__ ref, const float* __restrict__ mix,
                            float2* __restrict__ sph, float2* __restrict__ spht,
                            float2* __restrict__ mxs) {
  __shared__ float2 buf[4 * NFFT];
  int blk = blockIdx.x;
  int sig = blk / NCH4;
  int ch = blk - sig * NCH4;
  int t0 = ch * 4;
  int nv = min(4, NT - t0);
  int tid = threadIdx.x;
  bool is_ref = sig < NB * NSPK;
  int m = is_ref ? sig : (sig - NB * NSPK);
  const float* src = is_ref ? (ref + (size_t)m * LSIG) : (mix + (size_t)m * LSIG);

  for (int n = tid; n < NFFT; n += 256) {
    float w = __sinf(PI_F * (float)n / (float)NFFT);  // sqrt-hann
    int r = rev9(n);
    int g0 = t0 * HOPSZ + n - NFFT / 2;
#pragma unroll
    for (int j = 0; j < 4; ++j) {
      int gg = g0 + j * HOPSZ;
      float v = (j < nv && gg >= 0 && gg < LSIG) ? src[gg] : 0.0f;
      buf[j * NFFT + r] = make_float2(v * w, 0.0f);
    }
  }
  __syncthreads();
  fft512_quad(buf, tid, -1.0f);

  if (is_ref) {
    float2* d1 = sph + (size_t)m * NFREQ * NT;
    float2* d2 = spht + ((size_t)m * NT + t0) * NFREQ;
    for (int f = tid; f < NFREQ; f += 256) {
#pragma unroll
      for (int j = 0; j < 4; ++j) {
        if (j < nv) {
          float2 v = buf[j * NFFT + f];
          d1[(size_t)f * NT + t0 + j] = v;
          d2[(size_t)j * NFREQ + f] = v;
        }
      }
    }
  } else {
    float2* d1 = mxs + (size_t)m * NFREQ * NT;
    for (int f = tid; f < NFREQ; f += 256) {
#pragma unroll
      for (int j = 0; j < 4; ++j)
        if (j < nv) d1[(size_t)f * NT + t0 + j] = buf[j * NFFT + f];
    }
  }
}

// ---------------- power + fused per-batch max ----------------
__global__ void power_max_kernel(const float2* __restrict__ mxs, float* __restrict__ power,
                                 unsigned int* __restrict__ mx_u) {
  int blk = blockIdx.x;
  int b = blk / PM_BLOCKS_PER_B;
  int k = blk - b * PM_BLOCKS_PER_B;
  int r = k * 256 + threadIdx.x;
  float acc = 0.0f;
  if (r < NFREQ * NT) {
#pragma unroll
    for (int c = 0; c < NCHN; ++c) {
      float2 v = mxs[(size_t)(b * NCHN + c) * NFREQ * NT + r];
      acc += v.x * v.x + v.y * v.y;
    }
    acc *= (1.0f / (float)NCHN);
    power[(size_t)b * NFREQ * NT + r] = acc;
  }
  float m = acc;
#pragma unroll
  for (int off = 32; off > 0; off >>= 1) m = fmaxf(m, __shfl_down(m, off, 64));
  __shared__ float sm[4];
  int wave = threadIdx.x >> 6, lane = threadIdx.x & 63;
  if (lane == 0) sm[wave] = m;
  __syncthreads();
  if (threadIdx.x == 0) {
    float mm = fmaxf(fmaxf(sm[0], sm[1]), fmaxf(sm[2], sm[3]));
    atomicMax(&mx_u[b], __float_as_uint(mm));  // valid: all values >= 0
  }
}

// ---------------- R accumulation only (256 thr, 4-way t-split, ~11.5KB LDS) ----------------
// Loop body identical to the validated round-15 R path. 8 blocks/CU (wave cap),
// single grid pass (2056 blocks / 2048 slots).
__global__ void r_kernel(const float2* __restrict__ sph,
                         const float* __restrict__ power, const float* __restrict__ mx,
                         float2* __restrict__ R) {
  __shared__ float2 Ypad[YPAD_N];
  __shared__ float Wsh[NT];
  __shared__ float scratch[3 * NR_TILES * 8];   // cross-wave partials
  int g = blockIdx.x;
  int s = g & 1;
  int bf = g >> 1;
  int f = bf % NFREQ;
  int b = bf / NFREQ;
  int tid = threadIdx.x;

  const float2* yrow = sph + ((size_t)(b * NSPK + s) * NFREQ + f) * NT;
  const float* prow = power + ((size_t)b * NFREQ + f) * NT;
  float add = mx[b] * FCP_EPS_F + 1e-6f;
  for (int t = tid; t < NT; t += 256) Wsh[t] = 1.0f / (prow[t] + add);
  for (int i = tid; i < YPAD_N; i += 256) {
    bool in = (i >= TAPS - 1) && (i < TAPS - 1 + NT);
    Ypad[i] = in ? yrow[i - (TAPS - 1)] : make_float2(0.0f, 0.0f);
  }
  __syncthreads();

  const float invT = 1.0f / (float)NT;
  const int TQ[5] = {0, 126, 252, 378, NT};
  int wave = tid >> 6;
  int lane = tid & 63;
  bool isR = (lane < NR_TILES);

  float x00 = 0.f, y00 = 0.f, x01 = 0.f, y01 = 0.f;
  float x10 = 0.f, y10 = 0.f, x11 = 0.f, y11 = 0.f;
  int pb = 0, qb = 0;

  if (isR) {
    int tlo = TQ[wave], thi = TQ[wave + 1];
    int I = (int)((sqrtf(8.0f * (float)lane + 1.0f) - 1.0f) * 0.5f);
    while ((I + 1) * (I + 2) / 2 <= lane) ++I;
    while (I * (I + 1) / 2 > lane) --I;
    int J = lane - I * (I + 1) / 2;
    pb = 2 * I; qb = 2 * J;
    float2 a0 = Ypad[pb + tlo], a1 = Ypad[pb + tlo + 1];
    float2 b0 = Ypad[qb + tlo], b1 = Ypad[qb + tlo + 1];
    for (int t = tlo; t < thi; ++t) {
      float w = Wsh[t];
      float wax0 = w * a0.x, way0 = w * a0.y;
      float wax1 = w * a1.x, way1 = w * a1.y;
      x00 = fmaf(wax0, b0.x, fmaf(way0, b0.y, x00));
      y00 = fmaf(way0, b0.x, fmaf(-wax0, b0.y, y00));
      x01 = fmaf(wax0, b1.x, fmaf(way0, b1.y, x01));
      y01 = fmaf(way0, b1.x, fmaf(-wax0, b1.y, y01));
      x10 = fmaf(wax1, b0.x, fmaf(way1, b0.y, x10));
      y10 = fmaf(way1, b0.x, fmaf(-wax1, b0.y, y10));
      x11 = fmaf(wax1, b1.x, fmaf(way1, b1.y, x11));
      y11 = fmaf(way1, b1.x, fmaf(-wax1, b1.y, y11));
      a0 = a1; a1 = Ypad[pb + 2 + t];   // slide window
      b0 = b1; b1 = Ypad[qb + 2 + t];
    }
  }
  __syncthreads();

  if (isR && wave >= 1) {
    float* d = scratch + ((wave - 1) * NR_TILES + lane) * 8;
    d[0] = x00; d[1] = y00; d[2] = x01; d[3] = y01;
    d[4] = x10; d[5] = y10; d[6] = x11; d[7] = y11;
  }
  __syncthreads();

  if (isR && wave == 0) {
#pragma unroll
    for (int sgi = 0; sgi < 3; ++sgi) {
      const float* d = scratch + (sgi * NR_TILES + lane) * 8;
      x00 += d[0]; y00 += d[1]; x01 += d[2]; y01 += d[3];
      x10 += d[4]; y10 += d[5]; x11 += d[6]; y11 += d[7];
    }
    float2* Rg = R + (size_t)g * TAPS * TAPS;
#define STORE_R(p_, q_, xx, yy)                                       \
    if ((p_) >= (q_)) {                                                \
      float rx = (xx) * invT, ry = (yy) * invT;                        \
      Rg[(p_) * TAPS + (q_)] = make_float2(rx, ry);                    \
      if ((p_) != (q_)) Rg[(q_) * TAPS + (p_)] = make_float2(rx, -ry); \
    }
    STORE_R(pb, qb, x00, y00)
    STORE_R(pb, qb + 1, x01, y01)
    STORE_R(pb + 1, qb, x10, y10)
    STORE_R(pb + 1, qb + 1, x11, y11)
#undef STORE_R
  }
}

// ---------------- P accumulation only (256 thr, 4-way t-split) ----------------
// Loop body identical to the validated round-15 P path.
__global__ void p_kernel(const float2* __restrict__ sph, const float2* __restrict__ mxs,
                         const float* __restrict__ power, const float* __restrict__ mx,
                         float2* __restrict__ P) {
  __shared__ float2 Ypad[YPAD_N];
  __shared__ float2 MWsh[NCHN][NT];   // scratch after loops
  __shared__ float Wsh[NT];
  int g = blockIdx.x;
  int s = g & 1;
  int bf = g >> 1;
  int f = bf % NFREQ;
  int b = bf / NFREQ;
  int tid = threadIdx.x;

  const float2* yrow = sph + ((size_t)(b * NSPK + s) * NFREQ + f) * NT;
  const float* prow = power + ((size_t)b * NFREQ + f) * NT;
  float add = mx[b] * FCP_EPS_F + 1e-6f;
  for (int t = tid; t < NT; t += 256) Wsh[t] = 1.0f / (prow[t] + add);
  for (int i = tid; i < YPAD_N; i += 256) {
    bool in = (i >= TAPS - 1) && (i < TAPS - 1 + NT);
    Ypad[i] = in ? yrow[i - (TAPS - 1)] : make_float2(0.0f, 0.0f);
  }
  __syncthreads();
  for (int i = tid; i < NCHN * NT; i += 256) {
    int c = i / NT, t = i - c * NT;
    float2 m = mxs[((size_t)(b * NCHN + c) * NFREQ + f) * NT + t];
    float w = Wsh[t];
    MWsh[c][t] = make_float2(w * m.x, -w * m.y);
  }
  __syncthreads();

  const float invT = 1.0f / (float)NT;
  const int TQ[5] = {0, 126, 252, 378, NT};
  int wave = tid >> 6;
  int lane = tid & 63;
  bool isP = (lane < NP_THREADS);

  float x00 = 0.f, y00 = 0.f, x10 = 0.f, y10 = 0.f;
  int pb = 0, pc = 0;

  if (isP) {
    int tlo = TQ[wave], thi = TQ[wave + 1];
    int ih = lane / NCHN;
    pc = lane - ih * NCHN;
    pb = 2 * ih;
    float2 a0 = Ypad[pb + tlo], a1 = Ypad[pb + tlo + 1];
    const float2* MW = &MWsh[pc][0];
    for (int t = tlo; t < thi; ++t) {
      float2 mw = MW[t];
      x00 += a0.x * mw.x - a0.y * mw.y;
      y00 += a0.x * mw.y + a0.y * mw.x;
      x10 += a1.x * mw.x - a1.y * mw.y;
      y10 += a1.x * mw.y + a1.y * mw.x;
      a0 = a1; a1 = Ypad[pb + 2 + t];
    }
  }
  __syncthreads();    // all loop reads complete

  float* scratch = (float*)MWsh;  // dead now; need 720 floats
  if (isP && wave >= 1) {
    float* d = scratch + ((wave - 1) * NP_THREADS + lane) * 4;
    d[0] = x00; d[1] = y00; d[2] = x10; d[3] = y10;
  }
  __syncthreads();

  if (isP && wave == 0) {
#pragma unroll
    for (int sgi = 0; sgi < 3; ++sgi) {
      const float* d = scratch + (sgi * NP_THREADS + lane) * 4;
      x00 += d[0]; y00 += d[1]; x10 += d[2]; y10 += d[3];
    }
    float2* Pg = P + (size_t)g * TAPS * NCHN;
    Pg[pb * NCHN + pc] = make_float2(x00 * invT, y00 * invT);
    Pg[(pb + 1) * NCHN + pc] = make_float2(x10 * invT, y10 * invT);
  }
}

// ---------------- Cholesky solve (complex128; R+lambda*I is HPD) ----------------
__global__ void solve_kernel(const float2* __restrict__ R, const float2* __restrict__ P,
                             float* __restrict__ gout, float2* __restrict__ gct) {
  __shared__ double2 A[TAPS][TAPS];
  __shared__ double2 Bm[TAPS][NCHN];
  int g = blockIdx.x;
  int tid = threadIdx.x;
  int s = g & 1;
  int bf = g >> 1;
  int f = bf % NFREQ;
  int b = bf / NFREQ;
  int bs = b * NSPK + s;

  for (int i = tid; i < TAPS * TAPS; i += 64) {
    float2 r = R[(size_t)g * TAPS * TAPS + i];
    A[i / TAPS][i % TAPS] = make_double2((double)r.x, (double)r.y);
  }
  for (int i = tid; i < TAPS * NCHN; i += 64) {
    float2 p = P[(size_t)g * TAPS * NCHN + i];
    Bm[i / NCHN][i % NCHN] = make_double2((double)p.x, (double)p.y);
  }
  __syncthreads();
  if (tid < TAPS) A[tid][tid].x += LAMBDA_REG;
  __syncthreads();

  for (int k = 0; k < TAPS; ++k) {
    if (tid == 0) A[k][k].x = sqrt(A[k][k].x);
    __syncthreads();
    double d = A[k][k].x;
    if (tid > k && tid < TAPS) {
      A[tid][k].x /= d;
      A[tid][k].y /= d;
    }
    __syncthreads();
    int w = TAPS - 1 - k;
    for (int idx = tid; idx < w * w; idx += 64) {
      int i = k + 1 + idx / w;
      int j = k + 1 + idx % w;
      if (i >= j) {  // lower triangle only
        double2 a = A[i][k], bb = A[j][k];  // A[i][j] -= a * conj(bb)
        A[i][j].x -= a.x * bb.x + a.y * bb.y;
        A[i][j].y -= a.y * bb.x - a.x * bb.y;
      }
    }
    __syncthreads();
  }

  // 6 RHS: thread c handles column c
  if (tid < NCHN) {
    int c = tid;
    for (int k = 0; k < TAPS; ++k) {  // forward L y = B
      double sx = Bm[k][c].x, sy = Bm[k][c].y;
      for (int j = 0; j < k; ++j) {
        double2 l = A[k][j], y = Bm[j][c];
        sx -= l.x * y.x - l.y * y.y;
        sy -= l.x * y.y + l.y * y.x;
      }
      double d = A[k][k].x;
      Bm[k][c] = make_double2(sx / d, sy / d);
    }
    for (int k = TAPS - 1; k >= 0; --k) {  // backward L^H x = y
      double sx = Bm[k][c].x, sy = Bm[k][c].y;
      for (int j = k + 1; j < TAPS; ++j) {
        double2 l = A[j][k], xv = Bm[j][c];  // conj(l)*x
        sx -= l.x * xv.x + l.y * xv.y;
        sy -= l.x * xv.y - l.y * xv.x;
      }
      double d = A[k][k].x;
      Bm[k][c] = make_double2(sx / d, sy / d);
    }
  }
  __syncthreads();

  for (int i = tid; i < TAPS * NCHN; i += 64) {
    int p = i / NCHN, c = i - p * NCHN;
    double2 gv = Bm[p][c];
    float gx = (float)gv.x, gy = (float)(-gv.y);  // conj(G)
    gout[(size_t)g * TAPS * NCHN + i] = gx;       // float32, real part only
    gct[(((size_t)bs * TAPS + p) * NCHN + c) * NFREQ + f] = make_float2(gx, gy);
  }
}

// ---------------- ret + inverse FFT (quad-frame, XCD-swizzled) ----------------
__global__ void ret_ifft_kernel(const float2* __restrict__ spht, const float2* __restrict__ gct,
                                float* __restrict__ frames) {
  __shared__ float2 buf[4 * NFFT];
  constexpr int NBLK = NSIG * NCH4;
  int bid = blockIdx.x;
  int blk = (bid & 7) * (NBLK / 8) + (bid >> 3);  // XCD-aware swizzle
  int ch = blk % NCH4;
  int sc = blk / NCH4;
  int t0 = ch * 4;
  int nv = min(4, NT - t0);
  int c = sc % NCHN;
  int bs = sc / NCHN;
  int tid = threadIdx.x;

  const float2* gbase = gct + ((size_t)bs * TAPS * NCHN + c) * NFREQ;
  const float2* ysig = spht + (size_t)bs * NT * NFREQ;
  for (int f = tid; f < NFREQ; f += 256) {
    float sx0 = 0.f, sy0 = 0.f, sx1 = 0.f, sy1 = 0.f;
    float sx2 = 0.f, sy2 = 0.f, sx3 = 0.f, sy3 = 0.f;
    float2 g1p = make_float2(0.f, 0.f), g2p = make_float2(0.f, 0.f),
           g3p = make_float2(0.f, 0.f);
#pragma unroll
    for (int k = 0; k <= TAPS + 2; ++k) {  // frame j uses G[k-j]; ring holds zeros OOB
      int u = t0 - (TAPS - 1) + k;
      float2 y = (u >= 0 && u < NT) ? ysig[(size_t)u * NFREQ + f] : make_float2(0.f, 0.f);
      float2 gc = (k < TAPS) ? gbase[(size_t)k * NCHN * NFREQ + f] : make_float2(0.f, 0.f);
      sx0 += y.x * gc.x - y.y * gc.y;   sy0 += y.x * gc.y + y.y * gc.x;
      sx1 += y.x * g1p.x - y.y * g1p.y; sy1 += y.x * g1p.y + y.y * g1p.x;
      sx2 += y.x * g2p.x - y.y * g2p.y; sy2 += y.x * g2p.y + y.y * g2p.x;
      sx3 += y.x * g3p.x - y.y * g3p.y; sy3 += y.x * g3p.y + y.y * g3p.x;
      g3p = g2p; g2p = g1p; g1p = gc;
    }
    int r = rev9(f);
    buf[r] = make_float2(sx0, sy0);
    buf[NFFT + r] = make_float2(sx1, sy1);
    buf[2 * NFFT + r] = make_float2(sx2, sy2);
    buf[3 * NFFT + r] = make_float2(sx3, sy3);
    if (f > 0 && f < NFFT / 2) {
      int r2 = rev9(NFFT - f);
      buf[r2] = make_float2(sx0, -sy0);
      buf[NFFT + r2] = make_float2(sx1, -sy1);
      buf[2 * NFFT + r2] = make_float2(sx2, -sy2);
      buf[3 * NFFT + r2] = make_float2(sx3, -sy3);
    }
  }
  __syncthreads();
  fft512_quad(buf, tid, +1.0f);

  float* frow = frames + ((size_t)sc * NT + t0) * NFFT;
  for (int n = tid; n < NFFT; n += 256) {
    float w = __sinf(PI_F * (float)n / (float)NFFT);
#pragma unroll
    for (int j = 0; j < 4; ++j)
      if (j < nv) frow[(size_t)j * NFFT + n] = buf[j * NFFT + n].x * (1.0f / (float)NFFT) * w;
  }
}

// ---------------- overlap-add + env normalize + crop (float32 out) ----------------
__global__ void ola_kernel(const float* __restrict__ frames, float* __restrict__ out) {
  int i = blockIdx.x * 256 + threadIdx.x;
  if (i >= NSIG * LSIG) return;
  int sig = i / LSIG;
  int l = i - sig * LSIG;
  int lp = l + NFFT / 2;
  int j0 = max(0, (lp - (NFFT - HOPSZ)) / HOPSZ);
  int j1 = min(NT - 1, lp / HOPSZ);
  float acc = 0.0f;
  for (int j = j0; j <= j1; ++j) {
    int n = lp - j * HOPSZ;
    acc += frames[((size_t)sig * NT + j) * NFFT + n];
  }
  float env;
  if (j1 - j0 == 3) {
    env = 2.0f;  // sum sin^2(theta + k*pi/4), k=0..3 == 2 exactly
  } else {
    env = 0.0f;
    for (int j = j0; j <= j1; ++j) {
      int n = lp - j * HOPSZ;
      float w = __sinf(PI_F * (float)n / (float)NFFT);
      env += w * w;
    }
    if (env <= 1e-11f) env = 1.0f;
  }
  out[(size_t)G_ELEMS + i] = acc / env;
}

}  // namespace

extern "C" void kernel_launch(void* const* d_in, const int* in_sizes, int n_in,
                              void* d_out, int out_size, void* d_ws, size_t ws_size,
                              hipStream_t stream) {
  const float* ref = (const float*)d_in[0];
  const float* mix = (const float*)d_in[1];
  if (n_in >= 2 && in_sizes[0] > in_sizes[1]) {
    const float* tmp = ref; ref = mix; mix = tmp;
  }
  char* ws = (char*)d_ws;

  float2*  sph   = (float2*)(ws + SPH_B);
  float2*  spht  = (float2*)(ws + SPHT_B);
  float2*  mxs   = (float2*)(ws + MXS_B);
  float*   power = (float*)(ws + POW_B);
  float*   mx    = (float*)(ws + MX_B);
  float2*  R     = (float2*)(ws + R_B);
  float2*  P     = (float2*)(ws + P_B);
  float2*  gct   = (float2*)(ws + GCT_B);
  float*   frames= (float*)(ws + FRM_B);
  float*   out   = (float*)d_out;

  hipMemsetAsync(mx, 0, NB * sizeof(float), stream);  // mx accumulated via atomicMax
  stft_kernel<<<dim3((NB * NSPK + NB * NCHN) * NCH4), dim3(256), 0, stream>>>(ref, mix, sph, spht, mxs);
  power_max_kernel<<<dim3(NB * PM_BLOCKS_PER_B), dim3(256), 0, stream>>>(
      mxs, power, (unsigned int*)mx);
  r_kernel<<<dim3(NG), dim3(256), 0, stream>>>(sph, power, mx, R);
  p_kernel<<<dim3(NG), dim3(256), 0, stream>>>(sph, mxs, power, mx, P);
  solve_kernel<<<dim3(NG), dim3(64), 0, stream>>>(R, P, out, gct);
  ret_ifft_kernel<<<dim3(NSIG * NCH4), dim3(256), 0, stream>>>(spht, gct, frames);
  ola_kernel<<<dim3((NSIG * LSIG + 255) / 256), dim3(256), 0, stream>>>(frames, out);
}

// Round 23
// 291.589 us; speedup vs baseline: 1.0431x; 1.0431x over previous
//
#include <hip/hip_runtime.h>
#include <math.h>

namespace {

constexpr int NB = 4, NSPK = 2, NCHN = 6;
constexpr int LSIG = 64000;
constexpr int NFFT = 512, HOPSZ = 128, NFREQ = 257;
constexpr int NT = 505;               // frames
constexpr int TAPS = 20;
constexpr int NG = NB * NFREQ * NSPK; // 2056 systems
constexpr int NSIG = NB * NSPK * NCHN; // 48 istft signals
constexpr float PI_F = 3.14159265358979323846f;
constexpr double LAMBDA_REG = 2e-4;
constexpr float FCP_EPS_F = 1e-3f;
constexpr int G_ELEMS = NG * TAPS * NCHN; // 246720 floats (real part only)
constexpr int NCH4 = (NT + 3) / 4;    // 127 four-frame chunks (last has 1)
constexpr int YPAD_N = TAPS + 2 + NT; // 527: [0..18]=0, [19+u]=Y[u], tail zeros
constexpr int NR_TILES = 55;          // 2x2 tiles of lower triangle (10x10 tile grid)
constexpr int NP_THREADS = 60;        // 10 p-pairs x 6 channels
constexpr int PM_BLOCKS_PER_B = (NFREQ * NT + 255) / 256;  // 507 blocks per batch
constexpr int NFP = NFFT + NFFT / 64; // 520: padded FFT buffer (1 pad per 64)

constexpr size_t WS_ALIGN = 256;
constexpr size_t align_up(size_t x) { return (x + WS_ALIGN - 1) & ~(WS_ALIGN - 1); }

// ws byte offsets
constexpr size_t SPH_B  = 0;                                        // [8][257][505] float2
constexpr size_t SPH_SZ = (size_t)NB * NSPK * NFREQ * NT * 8;
constexpr size_t SPHT_B = align_up(SPH_B + SPH_SZ);                 // [8][505][257] float2
constexpr size_t MXS_B  = align_up(SPHT_B + SPH_SZ);                // [24][257][505] float2
constexpr size_t MXS_SZ = (size_t)NB * NCHN * NFREQ * NT * 8;
constexpr size_t POW_B  = align_up(MXS_B + MXS_SZ);                 // [4][257][505] float
constexpr size_t POW_SZ = (size_t)NB * NFREQ * NT * 4;
constexpr size_t MX_B   = align_up(POW_B + POW_SZ);                 // [4] float
constexpr size_t R_B    = align_up(MX_B + (size_t)NB * 4);          // [2056][400] float2
constexpr size_t R_SZ   = (size_t)NG * TAPS * TAPS * 8;
constexpr size_t P_B    = align_up(R_B + R_SZ);                     // [2056][120] float2
constexpr size_t P_SZ   = (size_t)NG * TAPS * NCHN * 8;
constexpr size_t GCT_B  = align_up(P_B + P_SZ);                     // [8][20][6][257] float2
constexpr size_t GCT_SZ = (size_t)NB * NSPK * TAPS * NCHN * NFREQ * 8;
constexpr size_t FRM_B  = align_up(GCT_B + GCT_SZ);                 // [48][505][512] float

__device__ __forceinline__ int rev9(int n) { return (int)(__brev((unsigned)n) >> 23); }
// Bank-conflict-breaking padded index (bijective, max 518 < 520).
__device__ __forceinline__ int BIX(int i) { return i + (i >> 6); }

// Quad in-LDS radix-2 DIT FFT, stage-pair fused, PADDED buffers (520/frame).
// Quartet strides {h,2h,3h} no longer alias 32-bank boundaries.
__device__ __forceinline__ void fft512_quad(float2* buf, int tid, float sign) {
#pragma unroll
  for (int s = 1; s <= 7; s += 2) {
    int h = 1 << (s - 1);
    int idx = tid & 127;
    int jb = (tid >> 7) * 2;          // this thread's buffer pair
    int pos = idx & (h - 1);
    int blk = idx >> (s - 1);
    int i0 = (blk << (s + 1)) + pos;
    float angA = sign * 2.0f * PI_F * (float)pos / (float)(2 * h);
    float angB = 0.5f * angA;
    float snA, csA, snB, csB;
    __sincosf(angA, &snA, &csA);
    __sincosf(angB, &snB, &csB);
    float csB2 = -sign * snB, snB2 = sign * csB;  // tw_B * (sign*i), exact
    int k0 = BIX(i0), k1 = BIX(i0 + h), k2 = BIX(i0 + 2 * h), k3 = BIX(i0 + 3 * h);
#pragma unroll
    for (int jj = 0; jj < 2; ++jj) {
      float2* bb = buf + (jb + jj) * NFP;
      float2 e0 = bb[k0], e1 = bb[k1], e2 = bb[k2], e3 = bb[k3];
      float2 t1 = make_float2(e1.x * csA - e1.y * snA, e1.x * snA + e1.y * csA);
      float2 t3 = make_float2(e3.x * csA - e3.y * snA, e3.x * snA + e3.y * csA);
      float2 p0 = make_float2(e0.x + t1.x, e0.y + t1.y);
      float2 p1 = make_float2(e0.x - t1.x, e0.y - t1.y);
      float2 p2 = make_float2(e2.x + t3.x, e2.y + t3.y);
      float2 p3 = make_float2(e2.x - t3.x, e2.y - t3.y);
      float2 u2 = make_float2(p2.x * csB - p2.y * snB, p2.x * snB + p2.y * csB);
      float2 u3 = make_float2(p3.x * csB2 - p3.y * snB2, p3.x * snB2 + p3.y * csB2);
      bb[k0] = make_float2(p0.x + u2.x, p0.y + u2.y);
      bb[k2] = make_float2(p0.x - u2.x, p0.y - u2.y);
      bb[k1] = make_float2(p1.x + u3.x, p1.y + u3.y);
      bb[k3] = make_float2(p1.x - u3.x, p1.y - u3.y);
    }
    __syncthreads();
  }
  {
    float ang = sign * 2.0f * PI_F * (float)tid / 512.0f;
    float sn, cs;
    __sincosf(ang, &sn, &cs);
    int k0 = BIX(tid), k1 = BIX(tid + 256);
#pragma unroll
    for (int j = 0; j < 4; ++j) {
      float2* bb = buf + j * NFP;
      float2 u = bb[k0], v = bb[k1];
      float2 vw = make_float2(v.x * cs - v.y * sn, v.x * sn + v.y * cs);
      bb[k0] = make_float2(u.x + vw.x, u.y + vw.y);
      bb[k1] = make_float2(u.x - vw.x, u.y - vw.y);
    }
    __syncthreads();
  }
}

// ---------------- STFT (quad-frame radix-2 FFT, padded LDS) ----------------
__global__ void stft_kernel(const float* __restrict__ ref, const float* __restrict__ mix,
                            float2* __restrict__ sph, float2* __restrict__ spht,
                            float2* __restrict__ mxs) {
  __shared__ float2 buf[4 * NFP];
  int blk = blockIdx.x;
  int sig = blk / NCH4;
  int ch = blk - sig * NCH4;
  int t0 = ch * 4;
  int nv = min(4, NT - t0);
  int tid = threadIdx.x;
  bool is_ref = sig < NB * NSPK;
  int m = is_ref ? sig : (sig - NB * NSPK);
  const float* src = is_ref ? (ref + (size_t)m * LSIG) : (mix + (size_t)m * LSIG);

  for (int n = tid; n < NFFT; n += 256) {
    float w = __sinf(PI_F * (float)n / (float)NFFT);  // sqrt-hann
    int r = BIX(rev9(n));
    int g0 = t0 * HOPSZ + n - NFFT / 2;
#pragma unroll
    for (int j = 0; j < 4; ++j) {
      int gg = g0 + j * HOPSZ;
      float v = (j < nv && gg >= 0 && gg < LSIG) ? src[gg] : 0.0f;
      buf[j * NFP + r] = make_float2(v * w, 0.0f);
    }
  }
  __syncthreads();
  fft512_quad(buf, tid, -1.0f);

  if (is_ref) {
    float2* d1 = sph + (size_t)m * NFREQ * NT;
    float2* d2 = spht + ((size_t)m * NT + t0) * NFREQ;
    for (int f = tid; f < NFREQ; f += 256) {
      int fb = BIX(f);
#pragma unroll
      for (int j = 0; j < 4; ++j) {
        if (j < nv) {
          float2 v = buf[j * NFP + fb];
          d1[(size_t)f * NT + t0 + j] = v;
          d2[(size_t)j * NFREQ + f] = v;
        }
      }
    }
  } else {
    float2* d1 = mxs + (size_t)m * NFREQ * NT;
    for (int f = tid; f < NFREQ; f += 256) {
      int fb = BIX(f);
#pragma unroll
      for (int j = 0; j < 4; ++j)
        if (j < nv) d1[(size_t)f * NT + t0 + j] = buf[j * NFP + fb];
    }
  }
}

// ---------------- power + fused per-batch max ----------------
__global__ void power_max_kernel(const float2* __restrict__ mxs, float* __restrict__ power,
                                 unsigned int* __restrict__ mx_u) {
  int blk = blockIdx.x;
  int b = blk / PM_BLOCKS_PER_B;
  int k = blk - b * PM_BLOCKS_PER_B;
  int r = k * 256 + threadIdx.x;
  float acc = 0.0f;
  if (r < NFREQ * NT) {
#pragma unroll
    for (int c = 0; c < NCHN; ++c) {
      float2 v = mxs[(size_t)(b * NCHN + c) * NFREQ * NT + r];
      acc += v.x * v.x + v.y * v.y;
    }
    acc *= (1.0f / (float)NCHN);
    power[(size_t)b * NFREQ * NT + r] = acc;
  }
  float m = acc;
#pragma unroll
  for (int off = 32; off > 0; off >>= 1) m = fmaxf(m, __shfl_down(m, off, 64));
  __shared__ float sm[4];
  int wave = threadIdx.x >> 6, lane = threadIdx.x & 63;
  if (lane == 0) sm[wave] = m;
  __syncthreads();
  if (threadIdx.x == 0) {
    float mm = fmaxf(fmaxf(sm[0], sm[1]), fmaxf(sm[2], sm[3]));
    atomicMax(&mx_u[b], __float_as_uint(mm));  // valid: all values >= 0
  }
}

// ---------------- R / P accumulation (register-tiled, 4-way t-split, 512 thr) ----------------
// Round-15/20 fused version — fastest measured (93.5 us).
__global__ void rp_kernel(const float2* __restrict__ sph, const float2* __restrict__ mxs,
                          const float* __restrict__ power, const float* __restrict__ mx,
                          float2* __restrict__ R, float2* __restrict__ P) {
  __shared__ float2 Ypad[YPAD_N];      // [0..18]=0, [19+u]=Y[u], tail zeros
  __shared__ float2 MWsh[NCHN][NT];    // w[t] * conj(M[c][t]); scratch after loops
  __shared__ float Wsh[NT];
  int g = blockIdx.x;
  int s = g & 1;
  int bf = g >> 1;
  int f = bf % NFREQ;
  int b = bf / NFREQ;
  int tid = threadIdx.x;

  const float2* yrow = sph + ((size_t)(b * NSPK + s) * NFREQ + f) * NT;
  const float* prow = power + ((size_t)b * NFREQ + f) * NT;
  float add = mx[b] * FCP_EPS_F + 1e-6f;
  for (int t = tid; t < NT; t += 512) Wsh[t] = 1.0f / (prow[t] + add);
  for (int i = tid; i < YPAD_N; i += 512) {
    bool in = (i >= TAPS - 1) && (i < TAPS - 1 + NT);
    Ypad[i] = in ? yrow[i - (TAPS - 1)] : make_float2(0.0f, 0.0f);
  }
  __syncthreads();
  for (int i = tid; i < NCHN * NT; i += 512) {
    int c = i / NT, t = i - c * NT;
    float2 m = mxs[((size_t)(b * NCHN + c) * NFREQ + f) * NT + t];
    float w = Wsh[t];
    MWsh[c][t] = make_float2(w * m.x, -w * m.y);
  }
  __syncthreads();

  const float invT = 1.0f / (float)NT;
  const int TQ[5] = {0, 126, 252, 378, NT};
  int wave = tid >> 6;
  int lane = tid & 63;
  bool isR = (wave < 4) && (lane < NR_TILES);
  bool isP = (wave >= 4) && (lane < NP_THREADS);

  float x00 = 0.f, y00 = 0.f, x01 = 0.f, y01 = 0.f;
  float x10 = 0.f, y10 = 0.f, x11 = 0.f, y11 = 0.f;
  int pb = 0, qb = 0, pc = 0;

  if (isR) {
    int seg = wave;
    int tlo = TQ[seg], thi = TQ[seg + 1];
    int I = (int)((sqrtf(8.0f * (float)lane + 1.0f) - 1.0f) * 0.5f);
    while ((I + 1) * (I + 2) / 2 <= lane) ++I;
    while (I * (I + 1) / 2 > lane) --I;
    int J = lane - I * (I + 1) / 2;
    pb = 2 * I; qb = 2 * J;
    float2 a0 = Ypad[pb + tlo], a1 = Ypad[pb + tlo + 1];
    float2 b0 = Ypad[qb + tlo], b1 = Ypad[qb + tlo + 1];
    for (int t = tlo; t < thi; ++t) {
      float w = Wsh[t];
      float wax0 = w * a0.x, way0 = w * a0.y;
      float wax1 = w * a1.x, way1 = w * a1.y;
      x00 = fmaf(wax0, b0.x, fmaf(way0, b0.y, x00));
      y00 = fmaf(way0, b0.x, fmaf(-wax0, b0.y, y00));
      x01 = fmaf(wax0, b1.x, fmaf(way0, b1.y, x01));
      y01 = fmaf(way0, b1.x, fmaf(-wax0, b1.y, y01));
      x10 = fmaf(wax1, b0.x, fmaf(way1, b0.y, x10));
      y10 = fmaf(way1, b0.x, fmaf(-wax1, b0.y, y10));
      x11 = fmaf(wax1, b1.x, fmaf(way1, b1.y, x11));
      y11 = fmaf(way1, b1.x, fmaf(-wax1, b1.y, y11));
      a0 = a1; a1 = Ypad[pb + 2 + t];   // slide window
      b0 = b1; b1 = Ypad[qb + 2 + t];
    }
  } else if (isP) {
    int seg = wave - 4;
    int tlo = TQ[seg], thi = TQ[seg + 1];
    int ih = lane / NCHN;
    pc = lane - ih * NCHN;
    pb = 2 * ih;
    float2 a0 = Ypad[pb + tlo], a1 = Ypad[pb + tlo + 1];
    const float2* MW = &MWsh[pc][0];
    for (int t = tlo; t < thi; ++t) {
      float2 mw = MW[t];
      x00 += a0.x * mw.x - a0.y * mw.y;
      y00 += a0.x * mw.y + a0.y * mw.x;
      x10 += a1.x * mw.x - a1.y * mw.y;
      y10 += a1.x * mw.y + a1.y * mw.x;
      a0 = a1; a1 = Ypad[pb + 2 + t];
    }
  }
  __syncthreads();    // all loop reads (Ypad, MWsh, Wsh) complete

  float* scratch = (float*)MWsh;  // dead now; need 2040 floats of 24240
  if (isR && wave >= 1) {
    float* d = scratch + ((wave - 1) * NR_TILES + lane) * 8;
    d[0] = x00; d[1] = y00; d[2] = x01; d[3] = y01;
    d[4] = x10; d[5] = y10; d[6] = x11; d[7] = y11;
  }
  if (isP && wave >= 5) {
    float* d = scratch + 3 * NR_TILES * 8 + ((wave - 5) * NP_THREADS + lane) * 4;
    d[0] = x00; d[1] = y00; d[2] = x10; d[3] = y10;
  }
  __syncthreads();

  if (isR && wave == 0) {
#pragma unroll
    for (int sgi = 0; sgi < 3; ++sgi) {
      const float* d = scratch + (sgi * NR_TILES + lane) * 8;
      x00 += d[0]; y00 += d[1]; x01 += d[2]; y01 += d[3];
      x10 += d[4]; y10 += d[5]; x11 += d[6]; y11 += d[7];
    }
    float2* Rg = R + (size_t)g * TAPS * TAPS;
#define STORE_R(p_, q_, xx, yy)                                       \
    if ((p_) >= (q_)) {                                                \
      float rx = (xx) * invT, ry = (yy) * invT;                        \
      Rg[(p_) * TAPS + (q_)] = make_float2(rx, ry);                    \
      if ((p_) != (q_)) Rg[(q_) * TAPS + (p_)] = make_float2(rx, -ry); \
    }
    STORE_R(pb, qb, x00, y00)
    STORE_R(pb, qb + 1, x01, y01)
    STORE_R(pb + 1, qb, x10, y10)
    STORE_R(pb + 1, qb + 1, x11, y11)
#undef STORE_R
  }
  if (isP && wave == 4) {
#pragma unroll
    for (int sgi = 0; sgi < 3; ++sgi) {
      const float* d = scratch + 3 * NR_TILES * 8 + (sgi * NP_THREADS + lane) * 4;
      x00 += d[0]; y00 += d[1]; x10 += d[2]; y10 += d[3];
    }
    float2* Pg = P + (size_t)g * TAPS * NCHN;
    Pg[pb * NCHN + pc] = make_float2(x00 * invT, y00 * invT);
    Pg[(pb + 1) * NCHN + pc] = make_float2(x10 * invT, y10 * invT);
  }
}

// ---------------- Cholesky solve (complex128; R+lambda*I is HPD) ----------------
__global__ void solve_kernel(const float2* __restrict__ R, const float2* __restrict__ P,
                             float* __restrict__ gout, float2* __restrict__ gct) {
  __shared__ double2 A[TAPS][TAPS];
  __shared__ double2 Bm[TAPS][NCHN];
  int g = blockIdx.x;
  int tid = threadIdx.x;
  int s = g & 1;
  int bf = g >> 1;
  int f = bf % NFREQ;
  int b = bf / NFREQ;
  int bs = b * NSPK + s;

  for (int i = tid; i < TAPS * TAPS; i += 64) {
    float2 r = R[(size_t)g * TAPS * TAPS + i];
    A[i / TAPS][i % TAPS] = make_double2((double)r.x, (double)r.y);
  }
  for (int i = tid; i < TAPS * NCHN; i += 64) {
    float2 p = P[(size_t)g * TAPS * NCHN + i];
    Bm[i / NCHN][i % NCHN] = make_double2((double)p.x, (double)p.y);
  }
  __syncthreads();
  if (tid < TAPS) A[tid][tid].x += LAMBDA_REG;
  __syncthreads();

  for (int k = 0; k < TAPS; ++k) {
    if (tid == 0) A[k][k].x = sqrt(A[k][k].x);
    __syncthreads();
    double d = A[k][k].x;
    if (tid > k && tid < TAPS) {
      A[tid][k].x /= d;
      A[tid][k].y /= d;
    }
    __syncthreads();
    int w = TAPS - 1 - k;
    for (int idx = tid; idx < w * w; idx += 64) {
      int i = k + 1 + idx / w;
      int j = k + 1 + idx % w;
      if (i >= j) {  // lower triangle only
        double2 a = A[i][k], bb = A[j][k];  // A[i][j] -= a * conj(bb)
        A[i][j].x -= a.x * bb.x + a.y * bb.y;
        A[i][j].y -= a.y * bb.x - a.x * bb.y;
      }
    }
    __syncthreads();
  }

  // 6 RHS: thread c handles column c
  if (tid < NCHN) {
    int c = tid;
    for (int k = 0; k < TAPS; ++k) {  // forward L y = B
      double sx = Bm[k][c].x, sy = Bm[k][c].y;
      for (int j = 0; j < k; ++j) {
        double2 l = A[k][j], y = Bm[j][c];
        sx -= l.x * y.x - l.y * y.y;
        sy -= l.x * y.y + l.y * y.x;
      }
      double d = A[k][k].x;
      Bm[k][c] = make_double2(sx / d, sy / d);
    }
    for (int k = TAPS - 1; k >= 0; --k) {  // backward L^H x = y
      double sx = Bm[k][c].x, sy = Bm[k][c].y;
      for (int j = k + 1; j < TAPS; ++j) {
        double2 l = A[j][k], xv = Bm[j][c];  // conj(l)*x
        sx -= l.x * xv.x + l.y * xv.y;
        sy -= l.x * xv.y - l.y * xv.x;
      }
      double d = A[k][k].x;
      Bm[k][c] = make_double2(sx / d, sy / d);
    }
  }
  __syncthreads();

  for (int i = tid; i < TAPS * NCHN; i += 64) {
    int p = i / NCHN, c = i - p * NCHN;
    double2 gv = Bm[p][c];
    float gx = (float)gv.x, gy = (float)(-gv.y);  // conj(G)
    gout[(size_t)g * TAPS * NCHN + i] = gx;       // float32, real part only
    gct[(((size_t)bs * TAPS + p) * NCHN + c) * NFREQ + f] = make_float2(gx, gy);
  }
}

// ---------------- ret + inverse FFT (quad-frame, XCD-swizzled, padded LDS) ----------------
__global__ void ret_ifft_kernel(const float2* __restrict__ spht, const float2* __restrict__ gct,
                                float* __restrict__ frames) {
  __shared__ float2 buf[4 * NFP];
  constexpr int NBLK = NSIG * NCH4;
  int bid = blockIdx.x;
  int blk = (bid & 7) * (NBLK / 8) + (bid >> 3);  // XCD-aware swizzle
  int ch = blk % NCH4;
  int sc = blk / NCH4;
  int t0 = ch * 4;
  int nv = min(4, NT - t0);
  int c = sc % NCHN;
  int bs = sc / NCHN;
  int tid = threadIdx.x;

  const float2* gbase = gct + ((size_t)bs * TAPS * NCHN + c) * NFREQ;
  const float2* ysig = spht + (size_t)bs * NT * NFREQ;
  for (int f = tid; f < NFREQ; f += 256) {
    float sx0 = 0.f, sy0 = 0.f, sx1 = 0.f, sy1 = 0.f;
    float sx2 = 0.f, sy2 = 0.f, sx3 = 0.f, sy3 = 0.f;
    float2 g1p = make_float2(0.f, 0.f), g2p = make_float2(0.f, 0.f),
           g3p = make_float2(0.f, 0.f);
#pragma unroll
    for (int k = 0; k <= TAPS + 2; ++k) {  // frame j uses G[k-j]; ring holds zeros OOB
      int u = t0 - (TAPS - 1) + k;
      float2 y = (u >= 0 && u < NT) ? ysig[(size_t)u * NFREQ + f] : make_float2(0.f, 0.f);
      float2 gc = (k < TAPS) ? gbase[(size_t)k * NCHN * NFREQ + f] : make_float2(0.f, 0.f);
      sx0 += y.x * gc.x - y.y * gc.y;   sy0 += y.x * gc.y + y.y * gc.x;
      sx1 += y.x * g1p.x - y.y * g1p.y; sy1 += y.x * g1p.y + y.y * g1p.x;
      sx2 += y.x * g2p.x - y.y * g2p.y; sy2 += y.x * g2p.y + y.y * g2p.x;
      sx3 += y.x * g3p.x - y.y * g3p.y; sy3 += y.x * g3p.y + y.y * g3p.x;
      g3p = g2p; g2p = g1p; g1p = gc;
    }
    int r = BIX(rev9(f));
    buf[r] = make_float2(sx0, sy0);
    buf[NFP + r] = make_float2(sx1, sy1);
    buf[2 * NFP + r] = make_float2(sx2, sy2);
    buf[3 * NFP + r] = make_float2(sx3, sy3);
    if (f > 0 && f < NFFT / 2) {
      int r2 = BIX(rev9(NFFT - f));
      buf[r2] = make_float2(sx0, -sy0);
      buf[NFP + r2] = make_float2(sx1, -sy1);
      buf[2 * NFP + r2] = make_float2(sx2, -sy2);
      buf[3 * NFP + r2] = make_float2(sx3, -sy3);
    }
  }
  __syncthreads();
  fft512_quad(buf, tid, +1.0f);

  float* frow = frames + ((size_t)sc * NT + t0) * NFFT;
  for (int n = tid; n < NFFT; n += 256) {
    float w = __sinf(PI_F * (float)n / (float)NFFT);
    int nb = BIX(n);
#pragma unroll
    for (int j = 0; j < 4; ++j)
      if (j < nv) frow[(size_t)j * NFFT + n] = buf[j * NFP + nb].x * (1.0f / (float)NFFT) * w;
  }
}

// ---------------- overlap-add + env normalize + crop (float32 out) ----------------
__global__ void ola_kernel(const float* __restrict__ frames, float* __restrict__ out) {
  int i = blockIdx.x * 256 + threadIdx.x;
  if (i >= NSIG * LSIG) return;
  int sig = i / LSIG;
  int l = i - sig * LSIG;
  int lp = l + NFFT / 2;
  int j0 = max(0, (lp - (NFFT - HOPSZ)) / HOPSZ);
  int j1 = min(NT - 1, lp / HOPSZ);
  float acc = 0.0f;
  for (int j = j0; j <= j1; ++j) {
    int n = lp - j * HOPSZ;
    acc += frames[((size_t)sig * NT + j) * NFFT + n];
  }
  float env;
  if (j1 - j0 == 3) {
    env = 2.0f;  // sum sin^2(theta + k*pi/4), k=0..3 == 2 exactly
  } else {
    env = 0.0f;
    for (int j = j0; j <= j1; ++j) {
      int n = lp - j * HOPSZ;
      float w = __sinf(PI_F * (float)n / (float)NFFT);
      env += w * w;
    }
    if (env <= 1e-11f) env = 1.0f;
  }
  out[(size_t)G_ELEMS + i] = acc / env;
}

}  // namespace

extern "C" void kernel_launch(void* const* d_in, const int* in_sizes, int n_in,
                              void* d_out, int out_size, void* d_ws, size_t ws_size,
                              hipStream_t stream) {
  const float* ref = (const float*)d_in[0];
  const float* mix = (const float*)d_in[1];
  if (n_in >= 2 && in_sizes[0] > in_sizes[1]) {
    const float* tmp = ref; ref = mix; mix = tmp;
  }
  char* ws = (char*)d_ws;

  float2*  sph   = (float2*)(ws + SPH_B);
  float2*  spht  = (float2*)(ws + SPHT_B);
  float2*  mxs   = (float2*)(ws + MXS_B);
  float*   power = (float*)(ws + POW_B);
  float*   mx    = (float*)(ws + MX_B);
  float2*  R     = (float2*)(ws + R_B);
  float2*  P     = (float2*)(ws + P_B);
  float2*  gct   = (float2*)(ws + GCT_B);
  float*   frames= (float*)(ws + FRM_B);
  float*   out   = (float*)d_out;

  hipMemsetAsync(mx, 0, NB * sizeof(float), stream);  // mx accumulated via atomicMax
  stft_kernel<<<dim3((NB * NSPK + NB * NCHN) * NCH4), dim3(256), 0, stream>>>(ref, mix, sph, spht, mxs);
  power_max_kernel<<<dim3(NB * PM_BLOCKS_PER_B), dim3(256), 0, stream>>>(
      mxs, power, (unsigned int*)mx);
  rp_kernel<<<dim3(NG), dim3(512), 0, stream>>>(sph, mxs, power, mx, R, P);
  solve_kernel<<<dim3(NG), dim3(64), 0, stream>>>(R, P, out, gct);
  ret_ifft_kernel<<<dim3(NSIG * NCH4), dim3(256), 0, stream>>>(spht, gct, frames);
  ola_kernel<<<dim3((NSIG * LSIG + 255) / 256), dim3(256), 0, stream>>>(frames, out);
}